// Round 1
// baseline (242.648 us; speedup 1.0000x reference)
//
#include <hip/hip_runtime.h>

// Problem constants
#define BATCH 1024
#define ITERS 20
#define SIGMA_C 0.1f
#define REG_C 1e-8f
// sizes: NZ=10, NE=80, NW=90, mI=180, B_hat 40x10

// ws layout (floats)
#define WS_B   0      // B_hat [40][10]
#define WS_QB  400    // Q_diag @ B_hat [40][10]
#define WS_QH  800    // Q_hat [10][10]
#define WS_Q   900    // Q [4][4]
#define WS_AH  916    // A_hat [40][4]

__device__ __forceinline__ float wave_sum(float v) {
    #pragma unroll
    for (int o = 32; o > 0; o >>= 1) v += __shfl_xor(v, o);
    return v;
}
__device__ __forceinline__ float wave_min(float v) {
    #pragma unroll
    for (int o = 32; o > 0; o >>= 1) v = fminf(v, __shfl_xor(v, o));
    return v;
}

__global__ __launch_bounds__(64) void setup_kernel(const float* __restrict__ Qs,
                                                   const float* __restrict__ Rs,
                                                   const float* __restrict__ Ad,
                                                   const float* __restrict__ Bd,
                                                   float* __restrict__ ws) {
    __shared__ float sApow[10][16];  // A^{i+1}
    __shared__ float sT[10][4];      // A^i B
    __shared__ float sB[40][10];     // B_hat
    __shared__ float sQ[16];         // Q
    __shared__ float sQB[40][10];    // Q_diag @ B_hat
    const int lane = threadIdx.x;

    if (lane == 0) {
        for (int e = 0; e < 16; ++e) sApow[0][e] = Ad[e];
        for (int i = 1; i < 10; ++i)
            for (int r = 0; r < 4; ++r)
                for (int c = 0; c < 4; ++c) {
                    float acc = 0.f;
                    for (int k = 0; k < 4; ++k) acc += sApow[i-1][r*4+k] * Ad[k*4+c];
                    sApow[i][r*4+c] = acc;
                }
        for (int r = 0; r < 4; ++r) sT[0][r] = Bd[r];
        for (int i = 1; i < 10; ++i)
            for (int r = 0; r < 4; ++r) {
                float acc = 0.f;
                for (int k = 0; k < 4; ++k) acc += Ad[r*4+k] * sT[i-1][k];
                sT[i][r] = acc;
            }
    }
    __syncthreads();
    // B_hat[4i+r][j] = (i>=j) ? (A^{i-j} B)[r] : 0
    for (int idx = lane; idx < 400; idx += 64) {
        int m = idx / 10, j = idx % 10;
        int i = m / 4, r = m % 4;
        sB[m][j] = (i >= j) ? sT[i-j][r] : 0.f;
    }
    for (int idx = lane; idx < 16; idx += 64) {
        int a = idx / 4, b = idx % 4;
        float acc = 0.f;
        for (int k = 0; k < 4; ++k) acc += Qs[a*4+k] * Qs[b*4+k];
        sQ[idx] = acc;
    }
    __syncthreads();
    // QB block i = Q @ Bblock_i
    for (int idx = lane; idx < 400; idx += 64) {
        int m = idx / 10, j = idx % 10;
        int i = m / 4, r = m % 4;
        float acc = 0.f;
        for (int c = 0; c < 4; ++c) acc += sQ[r*4+c] * sB[i*4+c][j];
        sQB[m][j] = acc;
    }
    __syncthreads();
    for (int idx = lane; idx < 400; idx += 64) {
        ws[WS_B  + idx] = sB[idx/10][idx%10];
        ws[WS_QB + idx] = sQB[idx/10][idx%10];
    }
    const float rsc = Rs[0] * Rs[0];
    for (int idx = lane; idx < 100; idx += 64) {
        int a = idx / 10, b = idx % 10;
        float acc = (a == b) ? rsc : 0.f;
        for (int m = 0; m < 40; ++m) acc += sB[m][a] * sQB[m][b];
        ws[WS_QH + idx] = acc;
    }
    for (int idx = lane; idx < 16; idx += 64) ws[WS_Q + idx] = sQ[idx];
    for (int idx = lane; idx < 160; idx += 64) {
        int m = idx / 4, c = idx % 4;
        ws[WS_AH + idx] = sApow[m/4][(m%4)*4 + c];
    }
}

// One wave (64 threads) per batch item.
// State layout (index i in [0,180)):
//   [0,10)   : +I rows on u (h=0.5)        [10,20) : -I rows on u (h=0.5)
//   [20,60)  : +B_hat rows  (h=4-ax)       [60,100): -B_hat rows (h=4+ax)
//   [100,180): -I rows on e (h=0)
__global__ __launch_bounds__(64) void ipm_kernel(const float* __restrict__ x,
                                                 const float* __restrict__ u0,
                                                 const float* __restrict__ ws,
                                                 float* __restrict__ out) {
    const int item = blockIdx.x;
    const int lane = threadIdx.x;

    __shared__ float B[40][10];
    __shared__ float Qh[10][10];
    __shared__ float ax[40];
    __shared__ float pv[10];
    __shared__ float w[90];
    __shared__ float s[180], lam[180];
    __shared__ float d[180], rp[180], tmp[180];
    __shared__ float rw[90], dw[90], ds_[180], dlam[180];
    __shared__ float D22[80], coeff[40], gv[40], Bu[40];
    __shared__ float S[10][13];
    __shared__ float sol[2][10];

    for (int idx = lane; idx < 400; idx += 64) B[idx/10][idx%10] = ws[WS_B + idx];
    for (int idx = lane; idx < 100; idx += 64) Qh[idx/10][idx%10] = ws[WS_QH + idx];

    const float* xi = x + item * 4;
    for (int idx = lane; idx < 40; idx += 64) {
        float acc = 0.f;
        #pragma unroll
        for (int c = 0; c < 4; ++c) acc += ws[WS_AH + idx*4 + c] * xi[c];
        ax[idx] = acc;
    }
    __syncthreads();
    for (int idx = lane; idx < 10; idx += 64) {
        float acc = 0.f;
        for (int m = 0; m < 40; ++m) acc += ax[m] * ws[WS_QB + m*10 + idx];
        pv[idx] = 2.f * acc;
    }
    for (int idx = lane; idx < 90; idx += 64) w[idx] = 0.f;
    for (int idx = lane; idx < 180; idx += 64) {
        lam[idx] = 1.f;
        float h;
        if      (idx < 20)  h = 0.5f;
        else if (idx < 60)  h = 4.f - ax[idx-20];
        else if (idx < 100) h = 4.f + ax[idx-60];
        else                h = 0.f;
        s[idx] = fmaxf(h, 1.f);
    }
    float nu = 0.f;
    const float uu0 = u0[item];
    __syncthreads();

    for (int it = 0; it < ITERS; ++it) {
        // d = lam/s, mu
        float slsum = 0.f;
        for (int idx = lane; idx < 180; idx += 64) {
            d[idx] = lam[idx] / s[idx];
            slsum += s[idx] * lam[idx];
        }
        const float mu = SIGMA_C * wave_sum(slsum) / 180.f;

        // Bu = B_hat @ w1
        for (int idx = lane; idx < 40; idx += 64) {
            float acc = 0.f;
            #pragma unroll
            for (int j = 0; j < 10; ++j) acc += B[idx][j] * w[j];
            Bu[idx] = acc;
        }
        __syncthreads();

        // r_prim = G w + s - h
        for (int idx = lane; idx < 180; idx += 64) {
            float gw, h;
            if      (idx < 10)  { gw =  w[idx];              h = 0.5f; }
            else if (idx < 20)  { gw = -w[idx-10];           h = 0.5f; }
            else if (idx < 60)  { int k = idx-20; gw =  Bu[k] - w[10+k]; h = 4.f - ax[k]; }
            else if (idx < 100) { int k = idx-60; gw = -Bu[k] - w[50+k]; h = 4.f + ax[k]; }
            else                { int k = idx-100; gw = -w[10+k];        h = 0.f; }
            rp[idx] = gw + s[idx] - h;
        }
        __syncthreads();
        // tmp = (mu - lam*s + lam*rp)/s
        for (int idx = lane; idx < 180; idx += 64)
            tmp[idx] = (mu - lam[idx]*s[idx] + lam[idx]*rp[idx]) / s[idx];
        __syncthreads();
        // gv[k] = (lam+tmp)[20+k] - (lam+tmp)[60+k]
        for (int idx = lane; idx < 40; idx += 64)
            gv[idx] = (lam[20+idx] + tmp[20+idx]) - (lam[60+idx] + tmp[60+idx]);
        __syncthreads();

        // rw = -(r_dual + G^T tmp); D22 diag
        for (int idx = lane; idx < 90; idx += 64) {
            if (idx < 10) {
                float acc = pv[idx] + (lam[idx] + tmp[idx]) - (lam[10+idx] + tmp[10+idx]);
                if (idx == 0) acc += nu;
                #pragma unroll
                for (int k = 0; k < 10; ++k) acc += 2.f * Qh[idx][k] * w[k];
                for (int k = 0; k < 40; ++k) acc += B[k][idx] * gv[k];
                rw[idx] = -acc;
            } else {
                int j = idx - 10;
                rw[idx] = -(2.f*w[idx] - lam[20+j] - lam[100+j] - tmp[20+j] - tmp[100+j]);
            }
        }
        for (int idx = lane; idx < 80; idx += 64)
            D22[idx] = 2.f + d[20+idx] + d[100+idx] + REG_C;
        __syncthreads();
        // coeff for Schur rank-1s; gv = M12-reduction of rhs
        for (int idx = lane; idx < 40; idx += 64) {
            float a2 = d[20+idx], b2 = d[60+idx];
            coeff[idx] = (a2 + b2) - a2*a2/D22[idx] - b2*b2/D22[40+idx];
            gv[idx]    = a2*rw[10+idx]/D22[idx] - b2*rw[50+idx]/D22[40+idx];
        }
        __syncthreads();

        // S = 2Qh + diag(d1a+d1b) + REG + sum_k coeff[k] * B_k B_k^T ; rhs cols 10 (rt1), 11 (e0)
        for (int idx = lane; idx < 100; idx += 64) {
            int r = idx / 10, c = idx % 10;
            float acc = 2.f * Qh[r][c];
            if (r == c) acc += d[r] + d[10+r] + REG_C;
            for (int k = 0; k < 40; ++k) acc += coeff[k] * B[k][r] * B[k][c];
            S[r][c] = acc;
        }
        for (int idx = lane; idx < 10; idx += 64) {
            float acc = rw[idx];
            for (int k = 0; k < 40; ++k) acc += B[k][idx] * gv[k];
            S[idx][10] = acc;
            S[idx][11] = (idx == 0) ? 1.f : 0.f;
        }
        __syncthreads();

        // Gaussian elimination (S is SPD, no pivoting), rows on lanes
        #pragma unroll
        for (int kc = 0; kc < 9; ++kc) {
            const float piv = S[kc][kc];
            if (lane > kc && lane < 10) {
                float f = S[lane][kc] / piv;
                for (int c = kc+1; c < 12; ++c) S[lane][c] -= f * S[kc][c];
            }
            __syncthreads();
        }
        // back-substitution, two rhs on lanes 0,1
        if (lane < 2) {
            float xx[10];
            #pragma unroll
            for (int r = 9; r >= 0; --r) {
                float acc = S[r][10 + lane];
                #pragma unroll
                for (int c = r+1; c < 10; ++c) acc -= S[r][c] * xx[c];
                xx[r] = acc / S[r][r];
            }
            #pragma unroll
            for (int r = 0; r < 10; ++r) sol[lane][r] = xx[r];
        }
        __syncthreads();

        const float rn   = -(w[0] - uu0);
        const float nu_d = (sol[0][0] - rn) / (sol[1][0] + REG_C);
        for (int idx = lane; idx < 10; idx += 64) dw[idx] = sol[0][idx] - nu_d * sol[1][idx];
        __syncthreads();
        // Bdw (reuse Bu)
        for (int idx = lane; idx < 40; idx += 64) {
            float acc = 0.f;
            #pragma unroll
            for (int j = 0; j < 10; ++j) acc += B[idx][j] * dw[j];
            Bu[idx] = acc;
        }
        __syncthreads();
        // dw2 = D22^{-1} (rw2 - M21 dw1)
        for (int idx = lane; idx < 40; idx += 64) {
            dw[10+idx] = (rw[10+idx] + d[20+idx]*Bu[idx]) / D22[idx];
            dw[50+idx] = (rw[50+idx] - d[60+idx]*Bu[idx]) / D22[40+idx];
        }
        __syncthreads();

        // ds = -(G dw) - rp ; dlam ; step ratios
        float rmin = 1.f;
        for (int idx = lane; idx < 180; idx += 64) {
            float gdw;
            if      (idx < 10)  gdw =  dw[idx];
            else if (idx < 20)  gdw = -dw[idx-10];
            else if (idx < 60)  { int k = idx-20; gdw =  Bu[k] - dw[10+k]; }
            else if (idx < 100) { int k = idx-60; gdw = -Bu[k] - dw[50+k]; }
            else                { int k = idx-100; gdw = -dw[10+k]; }
            float dsv = -gdw - rp[idx];
            float dlv = (mu - lam[idx]*s[idx] - lam[idx]*dsv) / s[idx];
            ds_[idx] = dsv; dlam[idx] = dlv;
            if (dsv < -1e-12f) rmin = fminf(rmin, -s[idx]   / fminf(dsv, -1e-12f));
            if (dlv < -1e-12f) rmin = fminf(rmin, -lam[idx] / fminf(dlv, -1e-12f));
        }
        const float alpha = 0.99f * wave_min(rmin);
        __syncthreads();
        for (int idx = lane; idx < 90; idx += 64)  w[idx] += alpha * dw[idx];
        for (int idx = lane; idx < 180; idx += 64) { s[idx] += alpha * ds_[idx]; lam[idx] += alpha * dlam[idx]; }
        nu += alpha * nu_d;
        __syncthreads();
    }

    // cost = u^T Qh u + p.u + sum_i ax_i^T Q ax_i + x0^T Q x0 + e.e
    float part = 0.f;
    for (int idx = lane; idx < 100; idx += 64) {
        int r = idx / 10, c = idx % 10;
        part += w[r] * Qh[r][c] * w[c];
    }
    for (int idx = lane; idx < 10; idx += 64) part += pv[idx] * w[idx];
    for (int idx = lane; idx < 160; idx += 64) {
        int i = idx / 16, rc = idx % 16, r = rc / 4, c = rc % 4;
        part += ax[i*4 + r] * ws[WS_Q + rc] * ax[i*4 + c];
    }
    for (int idx = lane; idx < 16; idx += 64) {
        int r = idx / 4, c = idx % 4;
        part += xi[r] * ws[WS_Q + idx] * xi[c];
    }
    for (int idx = lane; idx < 80; idx += 64) part += w[10+idx] * w[10+idx];
    const float cost = wave_sum(part);
    if (lane == 0) {
        out[item]         = cost;   // cost_opt
        out[BATCH + item] = w[0];   // u0_opt
    }
}

extern "C" void kernel_launch(void* const* d_in, const int* in_sizes, int n_in,
                              void* d_out, int out_size, void* d_ws, size_t ws_size,
                              hipStream_t stream) {
    const float* x  = (const float*)d_in[0];
    const float* u0 = (const float*)d_in[1];
    const float* Qs = (const float*)d_in[2];
    const float* Rs = (const float*)d_in[3];
    const float* Ad = (const float*)d_in[4];
    const float* Bd = (const float*)d_in[5];
    float* ws  = (float*)d_ws;
    float* out = (float*)d_out;

    setup_kernel<<<dim3(1), dim3(64), 0, stream>>>(Qs, Rs, Ad, Bd, ws);
    ipm_kernel<<<dim3(BATCH), dim3(64), 0, stream>>>(x, u0, ws, out);
}

// Round 2
// 141.499 us; speedup vs baseline: 1.7148x; 1.7148x over previous
//
#include <hip/hip_runtime.h>

#define BATCH 1024
#define ITERS 20
#define SIGMA_C 0.1f
#define REG_C 1e-8f

__device__ __forceinline__ float wave_sum(float v) {
    #pragma unroll
    for (int o = 32; o > 0; o >>= 1) v += __shfl_xor(v, o);
    return v;
}
__device__ __forceinline__ float wave_min(float v) {
    #pragma unroll
    for (int o = 32; o > 0; o >>= 1) v = fminf(v, __shfl_xor(v, o));
    return v;
}
__device__ __forceinline__ float frcp(float x) { return __builtin_amdgcn_rcpf(x); }

// One wave (64 lanes) per batch item. Lane k<40 owns constraint rows
// {B:20+k, C:60+k, D:100+k, E:140+k} and e-vars w2a=w[10+k], w2b=w[50+k].
// Lanes<20 own the u-box rows (idx=lane). w1[10] replicated in all lanes.
__global__ __launch_bounds__(64) void ipm_kernel(
    const float* __restrict__ x, const float* __restrict__ u0p,
    const float* __restrict__ Qs, const float* __restrict__ Rs,
    const float* __restrict__ Ad, const float* __restrict__ Bd,
    float* __restrict__ out)
{
    const int item = blockIdx.x;
    const int lane = threadIdx.x;

    __shared__ __align__(16) float TAB[110 * 44];  // rows 0..99: B_k[r]*B_k[c]; 100..109: B_k[r]
    __shared__ __align__(16) float QhL[10 * 12];
    __shared__ __align__(16) float SL[10 * 12];    // col 10 = rhs
    __shared__ __align__(16) float coeffL[44];
    __shared__ __align__(16) float gvcL[44];
    __shared__ float duL[20], ltL[20];
    __shared__ float axL[40], yL[40];
    __shared__ float pvL[10], wL[10];
    __shared__ float QL[16];
    __shared__ float TL[40];     // T[i][r] = (A^i B)[r]
    __shared__ float AhL[160];   // A_hat [40][4]
    __shared__ float QBL[400];   // (Q_diag B) [40][10]

    // ---------------- prologue ----------------
    const int r2 = (lane >> 2) & 3, c2 = lane & 3;
    const int r4 = lane & 3;

    // Q = Qs Qs^T
    if (lane < 16) {
        float acc = 0.f;
        #pragma unroll
        for (int k = 0; k < 4; ++k) acc += Qs[r2 * 4 + k] * Qs[c2 * 4 + k];
        QL[lane] = acc;
    }

    // A powers -> A_hat (shfl chain; every lane duplicates task lane&15)
    float acol[4];
    #pragma unroll
    for (int k = 0; k < 4; ++k) acol[k] = Ad[k * 4 + c2];
    float cur = Ad[r2 * 4 + c2];
    if (lane < 16) AhL[r2 * 4 + c2] = cur;
    #pragma unroll
    for (int i = 1; i < 10; ++i) {
        float nx = 0.f;
        #pragma unroll
        for (int k = 0; k < 4; ++k) nx += __shfl(cur, r2 * 4 + k) * acol[k];
        cur = nx;
        if (lane < 16) AhL[(4 * i + r2) * 4 + c2] = cur;
    }

    // T chain: T[0]=B, T[i]=A T[i-1]
    float arow[4];
    #pragma unroll
    for (int k = 0; k < 4; ++k) arow[k] = Ad[r4 * 4 + k];
    float tc = Bd[r4];
    if (lane < 4) TL[r4] = tc;
    #pragma unroll
    for (int i = 1; i < 10; ++i) {
        float nt = 0.f;
        #pragma unroll
        for (int k = 0; k < 4; ++k) nt += arow[k] * __shfl(tc, k);
        tc = nt;
        if (lane < 4) TL[i * 4 + r4] = nt;
    }
    __syncthreads();

    // B_hat row (lane<40): b[j] = (i>=j) ? T[i-j][r] : 0
    const int kk40 = (lane < 40) ? lane : 39;
    const int ib = lane >> 2;
    float b[10];
    #pragma unroll
    for (int j = 0; j < 10; ++j) {
        int dd = ib - j;
        int dc = dd < 0 ? 0 : (dd > 9 ? 9 : dd);
        float v = TL[dc * 4 + r4];
        b[j] = (dd >= 0 && lane < 40) ? v : 0.f;
    }

    // ax = A_hat x
    const float xv0 = x[item * 4 + 0], xv1 = x[item * 4 + 1];
    const float xv2 = x[item * 4 + 2], xv3 = x[item * 4 + 3];
    const float ax = AhL[kk40 * 4 + 0] * xv0 + AhL[kk40 * 4 + 1] * xv1 +
                     AhL[kk40 * 4 + 2] * xv2 + AhL[kk40 * 4 + 3] * xv3;
    if (lane < 40) axL[lane] = ax;

    // y = Q_diag ax ; qb = (Q_diag B) row (group-of-4 shfl)
    const int gbase = lane & ~3;
    float yv = 0.f;
    #pragma unroll
    for (int rp_ = 0; rp_ < 4; ++rp_) yv += QL[r4 * 4 + rp_] * __shfl(ax, gbase + rp_);
    if (lane < 40) yL[lane] = yv;
    #pragma unroll
    for (int cc = 0; cc < 10; ++cc) {
        float acc = 0.f;
        #pragma unroll
        for (int rp_ = 0; rp_ < 4; ++rp_) acc += QL[r4 * 4 + rp_] * __shfl(b[cc], gbase + rp_);
        if (lane < 40) QBL[lane * 10 + cc] = acc;
    }

    // TAB: outer products + B columns
    if (lane < 40) {
        #pragma unroll
        for (int rr = 0; rr < 10; ++rr) {
            const float br = b[rr];
            #pragma unroll
            for (int cc = 0; cc < 10; ++cc)
                TAB[(rr * 10 + cc) * 44 + lane] = br * b[cc];
        }
        #pragma unroll
        for (int j = 0; j < 10; ++j) TAB[(100 + j) * 44 + lane] = b[j];
    }
    for (int idx = lane; idx < 110 * 4; idx += 64)
        TAB[(idx >> 2) * 44 + 40 + (idx & 3)] = 0.f;
    if (lane < 4) { coeffL[40 + lane] = 0.f; gvcL[40 + lane] = 0.f; }
    __syncthreads();

    // pv and Qh
    const float R2v = Rs[0] * Rs[0];
    if (lane < 10) {
        float acc = 0.f;
        for (int k = 0; k < 40; ++k) acc += TAB[(100 + lane) * 44 + k] * yL[k];
        pvL[lane] = 2.f * acc;
    }
    #pragma unroll
    for (int p = 0; p < 2; ++p) {
        const int t = lane + 64 * p;
        if (t < 100) {
            const int aa = t / 10, bb = t - aa * 10;
            float acc = (aa == bb) ? R2v : 0.f;
            for (int m = 0; m < 40; ++m) acc += TAB[(100 + aa) * 44 + m] * QBL[m * 10 + bb];
            QhL[aa * 12 + bb] = acc;
        }
    }
    __syncthreads();

    // ---------------- state init ----------------
    float s_B = fmaxf(4.f - ax, 1.f), s_C = fmaxf(4.f + ax, 1.f);
    float s_D = 1.f, s_E = 1.f, s_U = 1.f;
    float l_B = 1.f, l_C = 1.f, l_D = 1.f, l_E = 1.f, l_U = 1.f;
    float w2a = 0.f, w2b = 0.f;
    float w1[10];
    #pragma unroll
    for (int r = 0; r < 10; ++r) w1[r] = 0.f;
    float w1own = 0.f, nu = 0.f;
    const float uu0 = u0p[item];
    const bool a40 = lane < 40, a20 = lane < 20;
    const int jown = (lane < 10) ? lane : lane - 10;
    const float sgnU = (lane < 10) ? 1.f : -1.f;

    // ---------------- IPM iterations ----------------
    for (int it = 0; it < ITERS; ++it) {
        const float rs_B = frcp(s_B), rs_C = frcp(s_C), rs_D = frcp(s_D),
                    rs_E = frcp(s_E), rs_U = frcp(s_U);
        const float d_B = l_B * rs_B, d_C = l_C * rs_C, d_D = l_D * rs_D,
                    d_E = l_E * rs_E, d_U = l_U * rs_U;
        float part = a40 ? (s_B * l_B + s_C * l_C + s_D * l_D + s_E * l_E) : 0.f;
        if (a20) part += s_U * l_U;
        const float mu = SIGMA_C * wave_sum(part) * (1.f / 180.f);

        float Bu = 0.f;
        #pragma unroll
        for (int j = 0; j < 10; ++j) Bu += b[j] * w1[j];

        const float rp_B = Bu - w2a + s_B - (4.f - ax);
        const float rp_C = -Bu - w2b + s_C - (4.f + ax);
        const float rp_D = -w2a + s_D;
        const float rp_E = -w2b + s_E;
        const float rp_U = sgnU * w1own + s_U - 0.5f;

        const float tm_B = (mu - l_B * s_B + l_B * rp_B) * rs_B;
        const float tm_C = (mu - l_C * s_C + l_C * rp_C) * rs_C;
        const float tm_D = (mu - l_D * s_D + l_D * rp_D) * rs_D;
        const float tm_E = (mu - l_E * s_E + l_E * rp_E) * rs_E;
        const float tm_U = (mu - l_U * s_U + l_U * rp_U) * rs_U;
        const float lt_B = l_B + tm_B, lt_C = l_C + tm_C, lt_D = l_D + tm_D,
                    lt_E = l_E + tm_E;

        const float D22a = 2.f + d_B + d_D + REG_C, D22b = 2.f + d_C + d_E + REG_C;
        const float rda = frcp(D22a), rdb = frcp(D22b);
        const float rw2a = -2.f * w2a + lt_B + lt_D;
        const float rw2b = -2.f * w2b + lt_C + lt_E;
        const float coeff = (d_B + d_C) - d_B * d_B * rda - d_C * d_C * rdb;
        const float gvc = (d_B * rw2a * rda - d_C * rw2b * rdb) - (lt_B - lt_C);

        if (a40) { coeffL[lane] = coeff; gvcL[lane] = gvc; }
        if (a20) { duL[lane] = d_U; ltL[lane] = l_U + tm_U; }
        __syncthreads();

        // S (100 tasks) + rhs (10 tasks)
        #pragma unroll
        for (int p = 0; p < 2; ++p) {
            const int t = lane + 64 * p;
            if (t < 110) {
                const float* vec = (t < 100) ? coeffL : gvcL;
                const float4* tab4 = reinterpret_cast<const float4*>(&TAB[t * 44]);
                const float4* v4 = reinterpret_cast<const float4*>(vec);
                float acc = 0.f;
                #pragma unroll
                for (int kk = 0; kk < 11; ++kk) {
                    const float4 av = tab4[kk], bv = v4[kk];
                    acc += av.x * bv.x + av.y * bv.y + av.z * bv.z + av.w * bv.w;
                }
                if (t < 100) {
                    const int rr = t / 10, cc = t - rr * 10;
                    float val = acc + 2.f * QhL[rr * 12 + cc];
                    if (rr == cc) val += duL[rr] + duL[10 + rr] + REG_C;
                    SL[rr * 12 + cc] = val;
                } else {
                    const int rr = t - 100;
                    float qw = 0.f;
                    #pragma unroll
                    for (int cc = 0; cc < 10; ++cc) qw += QhL[rr * 12 + cc] * w1[cc];
                    SL[rr * 12 + 10] =
                        acc - (2.f * qw + pvL[rr] + ltL[rr] - ltL[10 + rr] + (rr == 0 ? nu : 0.f));
                }
            }
        }
        __syncthreads();

        // register/shfl 10x10 solve, rows on lanes 0..9, 2 RHS
        float row[11], rB;
        if (lane < 10) {
            const float4* s4 = reinterpret_cast<const float4*>(&SL[lane * 12]);
            const float4 q0 = s4[0], q1 = s4[1], q2 = s4[2];
            row[0] = q0.x; row[1] = q0.y; row[2] = q0.z; row[3] = q0.w;
            row[4] = q1.x; row[5] = q1.y; row[6] = q1.z; row[7] = q1.w;
            row[8] = q2.x; row[9] = q2.y; row[10] = q2.z;
        } else {
            #pragma unroll
            for (int c = 0; c < 11; ++c) row[c] = 0.f;
        }
        rB = (lane == 0) ? 1.f : 0.f;

        #pragma unroll
        for (int kc = 0; kc < 9; ++kc) {
            float pk[10];
            #pragma unroll
            for (int c = kc; c < 10; ++c) pk[c] = __shfl(row[c], kc);
            const float pR = __shfl(row[10], kc);
            const float pBv = __shfl(rB, kc);
            const float f = (lane > kc) ? row[kc] * frcp(pk[kc]) : 0.f;
            #pragma unroll
            for (int c = kc + 1; c < 10; ++c) row[c] -= f * pk[c];
            row[10] -= f * pR;
            rB -= f * pBv;
        }

        float dwA[10], dwB[10], ownA = 0.f, ownB = 0.f;
        #pragma unroll
        for (int r = 9; r >= 0; --r) {
            const float rr_ = frcp(row[r]);
            const float vA = row[10] * rr_, vB = rB * rr_;
            const float bA = __shfl(vA, r), bB = __shfl(vB, r);
            dwA[r] = bA; dwB[r] = bB;
            if (jown == r) { ownA = bA; ownB = bB; }
            const float m_ = (lane < r) ? 1.f : 0.f;
            row[10] -= m_ * row[r] * bA;
            rB      -= m_ * row[r] * bB;
        }

        const float rn = -(w1[0] - uu0);
        const float nu_d = (dwA[0] - rn) / (dwB[0] + REG_C);
        float dw1[10];
        #pragma unroll
        for (int r = 0; r < 10; ++r) dw1[r] = dwA[r] - nu_d * dwB[r];
        const float dOwn = ownA - nu_d * ownB;

        float Bdw = 0.f;
        #pragma unroll
        for (int j = 0; j < 10; ++j) Bdw += b[j] * dw1[j];
        const float dw2a = (rw2a + d_B * Bdw) * rda;
        const float dw2b = (rw2b - d_C * Bdw) * rdb;

        const float ds_B = -(Bdw - dw2a) - rp_B;
        const float ds_C = (Bdw + dw2b) - rp_C;
        const float ds_D = dw2a - rp_D;
        const float ds_E = dw2b - rp_E;
        const float ds_U = -sgnU * dOwn - rp_U;
        const float dl_B = (mu - l_B * s_B - l_B * ds_B) * rs_B;
        const float dl_C = (mu - l_C * s_C - l_C * ds_C) * rs_C;
        const float dl_D = (mu - l_D * s_D - l_D * ds_D) * rs_D;
        const float dl_E = (mu - l_E * s_E - l_E * ds_E) * rs_E;
        const float dl_U = (mu - l_U * s_U - l_U * ds_U) * rs_U;

        float rmin = 1.f;
        if (a40) {
            if (ds_B < -1e-12f) rmin = fminf(rmin, -s_B / fminf(ds_B, -1e-12f));
            if (ds_C < -1e-12f) rmin = fminf(rmin, -s_C / fminf(ds_C, -1e-12f));
            if (ds_D < -1e-12f) rmin = fminf(rmin, -s_D / fminf(ds_D, -1e-12f));
            if (ds_E < -1e-12f) rmin = fminf(rmin, -s_E / fminf(ds_E, -1e-12f));
            if (dl_B < -1e-12f) rmin = fminf(rmin, -l_B / fminf(dl_B, -1e-12f));
            if (dl_C < -1e-12f) rmin = fminf(rmin, -l_C / fminf(dl_C, -1e-12f));
            if (dl_D < -1e-12f) rmin = fminf(rmin, -l_D / fminf(dl_D, -1e-12f));
            if (dl_E < -1e-12f) rmin = fminf(rmin, -l_E / fminf(dl_E, -1e-12f));
        }
        if (a20) {
            if (ds_U < -1e-12f) rmin = fminf(rmin, -s_U / fminf(ds_U, -1e-12f));
            if (dl_U < -1e-12f) rmin = fminf(rmin, -l_U / fminf(dl_U, -1e-12f));
        }
        const float alpha = 0.99f * wave_min(rmin);

        s_B += alpha * ds_B; s_C += alpha * ds_C; s_D += alpha * ds_D;
        s_E += alpha * ds_E; s_U += alpha * ds_U;
        l_B += alpha * dl_B; l_C += alpha * dl_C; l_D += alpha * dl_D;
        l_E += alpha * dl_E; l_U += alpha * dl_U;
        w2a += alpha * dw2a; w2b += alpha * dw2b;
        #pragma unroll
        for (int r = 0; r < 10; ++r) w1[r] += alpha * dw1[r];
        w1own += alpha * dOwn;
        nu += alpha * nu_d;
        __syncthreads();
    }

    // ---------------- epilogue: cost ----------------
    if (lane == 0) {
        #pragma unroll
        for (int r = 0; r < 10; ++r) wL[r] = w1[r];
    }
    __syncthreads();
    float part = a40 ? (w2a * w2a + w2b * w2b) : 0.f;
    for (int idx = lane; idx < 100; idx += 64) {
        const int r = idx / 10, c = idx - r * 10;
        part += wL[r] * QhL[r * 12 + c] * wL[c];
    }
    if (lane < 10) part += pvL[lane] * wL[lane];
    for (int idx = lane; idx < 160; idx += 64) {
        const int i2 = idx >> 4, rc = idx & 15, rr = rc >> 2, cc = rc & 3;
        part += axL[i2 * 4 + rr] * QL[rc] * axL[i2 * 4 + cc];
    }
    if (lane == 0) {
        float ct = 0.f;
        #pragma unroll
        for (int r = 0; r < 4; ++r) {
            const float xr = (r == 0 ? xv0 : r == 1 ? xv1 : r == 2 ? xv2 : xv3);
            #pragma unroll
            for (int c = 0; c < 4; ++c) {
                const float xc = (c == 0 ? xv0 : c == 1 ? xv1 : c == 2 ? xv2 : xv3);
                ct += xr * QL[r * 4 + c] * xc;
            }
        }
        part += ct;
    }
    const float cost = wave_sum(part);
    if (lane == 0) {
        out[item] = cost;
        out[BATCH + item] = w1[0];
    }
}

extern "C" void kernel_launch(void* const* d_in, const int* in_sizes, int n_in,
                              void* d_out, int out_size, void* d_ws, size_t ws_size,
                              hipStream_t stream) {
    const float* x  = (const float*)d_in[0];
    const float* u0 = (const float*)d_in[1];
    const float* Qs = (const float*)d_in[2];
    const float* Rs = (const float*)d_in[3];
    const float* Ad = (const float*)d_in[4];
    const float* Bd = (const float*)d_in[5];
    float* outp = (float*)d_out;
    ipm_kernel<<<dim3(BATCH), dim3(64), 0, stream>>>(x, u0, Qs, Rs, Ad, Bd, outp);
}

// Round 3
// 101.406 us; speedup vs baseline: 2.3928x; 1.3954x over previous
//
#include <hip/hip_runtime.h>

#define BATCH 1024
#define ITERS 20
#define SIGMA_C 0.1f
#define REG_C 1e-8f

__device__ __forceinline__ float frcp(float x) { return __builtin_amdgcn_rcpf(x); }
__device__ __forceinline__ float readlane_f(float v, int l) {
    return __int_as_float(__builtin_amdgcn_readlane(__float_as_int(v), l));
}
// DPP helper: ctrl must be a literal
#define DPPF(v, ctrl) \
    __int_as_float(__builtin_amdgcn_update_dpp(0, __float_as_int(v), ctrl, 0xf, 0xf, true))

__device__ __forceinline__ float wave_sum(float v) {
    v += DPPF(v, 0xB1);   // quad_perm 1,0,3,2  (xor1)
    v += DPPF(v, 0x4E);   // quad_perm 2,3,0,1  (xor2)
    v += DPPF(v, 0x141);  // row_half_mirror    (xor4-equivalent pairing)
    v += DPPF(v, 0x140);  // row_mirror         (xor8-equivalent pairing)
    v += __shfl_xor(v, 16);
    v += __shfl_xor(v, 32);
    return v;
}
__device__ __forceinline__ float wave_min(float v) {
    v = fminf(v, DPPF(v, 0xB1));
    v = fminf(v, DPPF(v, 0x4E));
    v = fminf(v, DPPF(v, 0x141));
    v = fminf(v, DPPF(v, 0x140));
    v = fminf(v, __shfl_xor(v, 16));
    v = fminf(v, __shfl_xor(v, 32));
    return v;
}

// One wave (64 lanes) per batch item. Lane k<40 owns constraint rows
// {B:20+k, C:60+k, D:100+k, E:140+k} and e-vars w2a=w[10+k], w2b=w[50+k].
// Lanes<20 own the u-box rows. w1[10] replicated in all lanes.
// S-formation: lanes 0-49 each own 2 adjacent S entries (register-cached
// outer-product rows), lanes 50-59 own the 10 rhs entries.
__global__ __launch_bounds__(64, 1) void ipm_kernel(
    const float* __restrict__ x, const float* __restrict__ u0p,
    const float* __restrict__ Qs, const float* __restrict__ Rs,
    const float* __restrict__ Ad, const float* __restrict__ Bd,
    float* __restrict__ out)
{
    const int item = blockIdx.x;
    const int lane = threadIdx.x;

    __shared__ __align__(16) float BLc[10 * 40];  // B column-major: BLc[j][k]=B[k][j]
    __shared__ __align__(16) float QBc[10 * 40];  // (Q_diag B) column-major
    __shared__ __align__(16) float yL4[40];
    __shared__ __align__(16) float QhL[10 * 12];
    __shared__ __align__(16) float SL[10 * 12];   // col 10 = rhs
    __shared__ __align__(16) float cg[80];        // [0,40)=coeff, [40,80)=gvc
    __shared__ float duL[20], ltL[20];
    __shared__ float axL[40];
    __shared__ float pvL[10], wL[10];
    __shared__ float QL[16];
    __shared__ float TL[40];    // T[i][r] = (A^i B)[r]
    __shared__ float AhL[160];  // A_hat [40][4]

    // ---------------- prologue ----------------
    const int r2 = (lane >> 2) & 3, c2 = lane & 3;
    const int r4 = lane & 3;

    if (lane < 16) {
        float acc = 0.f;
        #pragma unroll
        for (int k = 0; k < 4; ++k) acc += Qs[r2 * 4 + k] * Qs[c2 * 4 + k];
        QL[lane] = acc;
    }

    // A powers -> A_hat (shfl chain)
    float acol[4];
    #pragma unroll
    for (int k = 0; k < 4; ++k) acol[k] = Ad[k * 4 + c2];
    float cur = Ad[r2 * 4 + c2];
    if (lane < 16) AhL[r2 * 4 + c2] = cur;
    #pragma unroll
    for (int i = 1; i < 10; ++i) {
        float nx = 0.f;
        #pragma unroll
        for (int k = 0; k < 4; ++k) nx += __shfl(cur, r2 * 4 + k) * acol[k];
        cur = nx;
        if (lane < 16) AhL[(4 * i + r2) * 4 + c2] = cur;
    }

    // T chain
    float arow[4];
    #pragma unroll
    for (int k = 0; k < 4; ++k) arow[k] = Ad[r4 * 4 + k];
    float tc = Bd[r4];
    if (lane < 4) TL[r4] = tc;
    #pragma unroll
    for (int i = 1; i < 10; ++i) {
        float nt = 0.f;
        #pragma unroll
        for (int k = 0; k < 4; ++k) nt += arow[k] * __shfl(tc, k);
        tc = nt;
        if (lane < 4) TL[i * 4 + r4] = nt;
    }
    __syncthreads();

    // per-lane B_hat row
    const int kk40 = (lane < 40) ? lane : 39;
    const int ib = lane >> 2;
    float b[10];
    #pragma unroll
    for (int j = 0; j < 10; ++j) {
        int dd = ib - j;
        int dc = dd < 0 ? 0 : (dd > 9 ? 9 : dd);
        float v = TL[dc * 4 + r4];
        b[j] = (dd >= 0 && lane < 40) ? v : 0.f;
    }

    const float xv0 = x[item * 4 + 0], xv1 = x[item * 4 + 1];
    const float xv2 = x[item * 4 + 2], xv3 = x[item * 4 + 3];
    const float ax = AhL[kk40 * 4 + 0] * xv0 + AhL[kk40 * 4 + 1] * xv1 +
                     AhL[kk40 * 4 + 2] * xv2 + AhL[kk40 * 4 + 3] * xv3;
    if (lane < 40) axL[lane] = ax;

    const int gbase = lane & ~3;
    float yv = 0.f;
    #pragma unroll
    for (int rp_ = 0; rp_ < 4; ++rp_) yv += QL[r4 * 4 + rp_] * __shfl(ax, gbase + rp_);
    if (lane < 40) yL4[lane] = yv;
    #pragma unroll
    for (int cc = 0; cc < 10; ++cc) {
        float acc = 0.f;
        #pragma unroll
        for (int rp_ = 0; rp_ < 4; ++rp_) acc += QL[r4 * 4 + rp_] * __shfl(b[cc], gbase + rp_);
        if (lane < 40) QBc[cc * 40 + lane] = acc;
    }
    if (lane < 40) {
        #pragma unroll
        for (int j = 0; j < 10; ++j) BLc[j * 40 + lane] = b[j];
    }
    __syncthreads();

    // pv (lanes 0-9)
    if (lane < 10) {
        const float4* br = reinterpret_cast<const float4*>(&BLc[lane * 40]);
        const float4* yy = reinterpret_cast<const float4*>(yL4);
        float acc = 0.f;
        #pragma unroll
        for (int i = 0; i < 10; ++i) {
            const float4 a_ = br[i], b_ = yy[i];
            acc += a_.x * b_.x + a_.y * b_.y + a_.z * b_.z + a_.w * b_.w;
        }
        pvL[lane] = 2.f * acc;
    }
    // Qh (100 tasks)
    const float R2v = Rs[0] * Rs[0];
    #pragma unroll
    for (int p = 0; p < 2; ++p) {
        const int t = lane + 64 * p;
        if (t < 100) {
            const int aa = t / 10, bb = t - aa * 10;
            const float4* ba = reinterpret_cast<const float4*>(&BLc[aa * 40]);
            const float4* qb = reinterpret_cast<const float4*>(&QBc[bb * 40]);
            float acc = (aa == bb) ? R2v : 0.f;
            #pragma unroll
            for (int i = 0; i < 10; ++i) {
                const float4 a_ = ba[i], b_ = qb[i];
                acc += a_.x * b_.x + a_.y * b_.y + a_.z * b_.z + a_.w * b_.w;
            }
            QhL[aa * 12 + bb] = acc;
        }
    }
    __syncthreads();

    // ---------------- per-lane register task caches ----------------
    const int t1 = 2 * lane;
    const int srow = t1 / 10, sc1 = t1 - srow * 10, sc2 = sc1 + 1;
    const int rr = lane - 50;
    float tabA[40], tabB[40];
    float qh_a = 0.f, qh_b = 0.f;
    bool diagA = false, diagB = false;
    int drow = 0;
    if (lane < 50) {
        const float4* br = reinterpret_cast<const float4*>(&BLc[srow * 40]);
        const float4* b1 = reinterpret_cast<const float4*>(&BLc[sc1 * 40]);
        const float4* b2 = reinterpret_cast<const float4*>(&BLc[sc2 * 40]);
        #pragma unroll
        for (int i = 0; i < 10; ++i) {
            const float4 r_ = br[i], u_ = b1[i], v_ = b2[i];
            tabA[4*i+0] = r_.x * u_.x; tabA[4*i+1] = r_.y * u_.y;
            tabA[4*i+2] = r_.z * u_.z; tabA[4*i+3] = r_.w * u_.w;
            tabB[4*i+0] = r_.x * v_.x; tabB[4*i+1] = r_.y * v_.y;
            tabB[4*i+2] = r_.z * v_.z; tabB[4*i+3] = r_.w * v_.w;
        }
        qh_a = 2.f * QhL[srow * 12 + sc1];
        qh_b = 2.f * QhL[srow * 12 + sc2];
        diagA = (srow == sc1); diagB = (srow == sc2);
        drow = srow;
    } else if (lane < 60) {
        const float4* br = reinterpret_cast<const float4*>(&BLc[rr * 40]);
        #pragma unroll
        for (int i = 0; i < 10; ++i) {
            const float4 r_ = br[i];
            tabA[4*i+0] = r_.x; tabA[4*i+1] = r_.y;
            tabA[4*i+2] = r_.z; tabA[4*i+3] = r_.w;
        }
        #pragma unroll
        for (int c = 0; c < 10; ++c) tabB[c] = QhL[rr * 12 + c];
        qh_a = pvL[rr];
    }
    __syncthreads();

    // ---------------- state init ----------------
    float s_B = fmaxf(4.f - ax, 1.f), s_C = fmaxf(4.f + ax, 1.f);
    float s_D = 1.f, s_E = 1.f, s_U = 1.f;
    float l_B = 1.f, l_C = 1.f, l_D = 1.f, l_E = 1.f, l_U = 1.f;
    float w2a = 0.f, w2b = 0.f;
    float w1[10];
    #pragma unroll
    for (int r = 0; r < 10; ++r) w1[r] = 0.f;
    float w1own = 0.f, nu = 0.f;
    const float uu0 = u0p[item];
    const bool a40 = lane < 40, a20 = lane < 20;
    const int jown = (lane < 10) ? lane : lane - 10;
    const float sgnU = (lane < 10) ? 1.f : -1.f;

    // ---------------- IPM iterations ----------------
    for (int it = 0; it < ITERS; ++it) {
        const float rs_B = frcp(s_B), rs_C = frcp(s_C), rs_D = frcp(s_D),
                    rs_E = frcp(s_E), rs_U = frcp(s_U);
        const float d_B = l_B * rs_B, d_C = l_C * rs_C, d_D = l_D * rs_D,
                    d_E = l_E * rs_E, d_U = l_U * rs_U;
        float part = a40 ? (s_B * l_B + s_C * l_C + s_D * l_D + s_E * l_E) : 0.f;
        if (a20) part += s_U * l_U;
        const float mu = SIGMA_C * wave_sum(part) * (1.f / 180.f);

        float Bu = 0.f;
        #pragma unroll
        for (int j = 0; j < 10; ++j) Bu += b[j] * w1[j];

        const float rp_B = Bu - w2a + s_B - (4.f - ax);
        const float rp_C = -Bu - w2b + s_C - (4.f + ax);
        const float rp_D = -w2a + s_D;
        const float rp_E = -w2b + s_E;
        const float rp_U = sgnU * w1own + s_U - 0.5f;

        const float tm_B = (mu - l_B * s_B + l_B * rp_B) * rs_B;
        const float tm_C = (mu - l_C * s_C + l_C * rp_C) * rs_C;
        const float tm_D = (mu - l_D * s_D + l_D * rp_D) * rs_D;
        const float tm_E = (mu - l_E * s_E + l_E * rp_E) * rs_E;
        const float tm_U = (mu - l_U * s_U + l_U * rp_U) * rs_U;
        const float lt_B = l_B + tm_B, lt_C = l_C + tm_C, lt_D = l_D + tm_D,
                    lt_E = l_E + tm_E;

        const float D22a = 2.f + d_B + d_D + REG_C, D22b = 2.f + d_C + d_E + REG_C;
        const float rda = frcp(D22a), rdb = frcp(D22b);
        const float rw2a = -2.f * w2a + lt_B + lt_D;
        const float rw2b = -2.f * w2b + lt_C + lt_E;
        const float coeff = (d_B + d_C) - d_B * d_B * rda - d_C * d_C * rdb;
        const float gvc = (d_B * rw2a * rda - d_C * rw2b * rdb) - (lt_B - lt_C);

        if (a40) { cg[lane] = coeff; cg[40 + lane] = gvc; }
        if (a20) { duL[lane] = d_U; ltL[lane] = l_U + tm_U; }
        __syncthreads();

        // ---- S + rhs formation (register tables, broadcast coeff reads) ----
        float4 cf[10];
        {
            const float4* cp = reinterpret_cast<const float4*>(cg + ((lane >= 50) ? 40 : 0));
            #pragma unroll
            for (int i = 0; i < 10; ++i) cf[i] = cp[i];
        }
        if (lane < 50) {
            float accA = 0.f, accB = 0.f;
            #pragma unroll
            for (int i = 0; i < 10; ++i) {
                accA += tabA[4*i+0]*cf[i].x + tabA[4*i+1]*cf[i].y +
                        tabA[4*i+2]*cf[i].z + tabA[4*i+3]*cf[i].w;
                accB += tabB[4*i+0]*cf[i].x + tabB[4*i+1]*cf[i].y +
                        tabB[4*i+2]*cf[i].z + tabB[4*i+3]*cf[i].w;
            }
            float vA = accA + qh_a, vB = accB + qh_b;
            if (diagA || diagB) {
                const float dd = duL[drow] + duL[10 + drow] + REG_C;
                if (diagA) vA += dd; else vB += dd;
            }
            *reinterpret_cast<float2*>(&SL[srow * 12 + sc1]) = make_float2(vA, vB);
        } else if (lane < 60) {
            float acc = 0.f;
            #pragma unroll
            for (int i = 0; i < 10; ++i)
                acc += tabA[4*i+0]*cf[i].x + tabA[4*i+1]*cf[i].y +
                       tabA[4*i+2]*cf[i].z + tabA[4*i+3]*cf[i].w;
            float qw = 0.f;
            #pragma unroll
            for (int c = 0; c < 10; ++c) qw += tabB[c] * w1[c];
            SL[rr * 12 + 10] =
                acc - (2.f * qw + qh_a + ltL[rr] - ltL[10 + rr] + ((rr == 0) ? nu : 0.f));
        }
        __syncthreads();

        // ---- 10x10 solve: rows on lanes 0-9, readlane broadcasts, 2 RHS ----
        float row[11], rBv;
        if (lane < 10) {
            const float4* s4 = reinterpret_cast<const float4*>(&SL[lane * 12]);
            const float4 q0 = s4[0], q1 = s4[1], q2 = s4[2];
            row[0] = q0.x; row[1] = q0.y; row[2] = q0.z; row[3] = q0.w;
            row[4] = q1.x; row[5] = q1.y; row[6] = q1.z; row[7] = q1.w;
            row[8] = q2.x; row[9] = q2.y; row[10] = q2.z;
        } else {
            #pragma unroll
            for (int c = 0; c < 11; ++c) row[c] = 0.f;
        }
        rBv = (lane == 0) ? 1.f : 0.f;

        #pragma unroll
        for (int kc = 0; kc < 9; ++kc) {
            float pk[11];
            #pragma unroll
            for (int c = kc; c < 11; ++c) pk[c] = readlane_f(row[c], kc);
            const float pB = readlane_f(rBv, kc);
            const float rpiv = frcp(pk[kc]);
            const float f = (lane > kc) ? row[kc] * rpiv : 0.f;
            #pragma unroll
            for (int c = kc + 1; c < 11; ++c) row[c] -= f * pk[c];
            rBv -= f * pB;
        }

        // hoisted diag reciprocals (row coeffs are final now)
        float rd[10];
        #pragma unroll
        for (int r = 0; r < 10; ++r) rd[r] = frcp(row[r]);

        float dwAv[10], dwBv[10], ownA = 0.f, ownB = 0.f;
        #pragma unroll
        for (int r = 9; r >= 0; --r) {
            const float bA = readlane_f(row[10] * rd[r], r);
            const float bB = readlane_f(rBv * rd[r], r);
            dwAv[r] = bA; dwBv[r] = bB;
            if (jown == r) { ownA = bA; ownB = bB; }
            const float m_ = (lane < r) ? 1.f : 0.f;
            row[10] -= m_ * row[r] * bA;
            rBv     -= m_ * row[r] * bB;
        }

        const float rn = -(w1[0] - uu0);
        const float nu_d = (dwAv[0] - rn) * frcp(dwBv[0] + REG_C);
        float dw1[10];
        #pragma unroll
        for (int r = 0; r < 10; ++r) dw1[r] = dwAv[r] - nu_d * dwBv[r];
        const float dOwn = ownA - nu_d * ownB;

        float Bdw = 0.f;
        #pragma unroll
        for (int j = 0; j < 10; ++j) Bdw += b[j] * dw1[j];
        const float dw2a = (rw2a + d_B * Bdw) * rda;
        const float dw2b = (rw2b - d_C * Bdw) * rdb;

        const float ds_B = -(Bdw - dw2a) - rp_B;
        const float ds_C = (Bdw + dw2b) - rp_C;
        const float ds_D = dw2a - rp_D;
        const float ds_E = dw2b - rp_E;
        const float ds_U = -sgnU * dOwn - rp_U;
        const float dl_B = (mu - l_B * s_B - l_B * ds_B) * rs_B;
        const float dl_C = (mu - l_C * s_C - l_C * ds_C) * rs_C;
        const float dl_D = (mu - l_D * s_D - l_D * ds_D) * rs_D;
        const float dl_E = (mu - l_E * s_E - l_E * ds_E) * rs_E;
        const float dl_U = (mu - l_U * s_U - l_U * ds_U) * rs_U;

        float rmin = 1.f;
        if (a40) {
            if (ds_B < -1e-12f) rmin = fminf(rmin, -s_B * frcp(ds_B));
            if (ds_C < -1e-12f) rmin = fminf(rmin, -s_C * frcp(ds_C));
            if (ds_D < -1e-12f) rmin = fminf(rmin, -s_D * frcp(ds_D));
            if (ds_E < -1e-12f) rmin = fminf(rmin, -s_E * frcp(ds_E));
            if (dl_B < -1e-12f) rmin = fminf(rmin, -l_B * frcp(dl_B));
            if (dl_C < -1e-12f) rmin = fminf(rmin, -l_C * frcp(dl_C));
            if (dl_D < -1e-12f) rmin = fminf(rmin, -l_D * frcp(dl_D));
            if (dl_E < -1e-12f) rmin = fminf(rmin, -l_E * frcp(dl_E));
        }
        if (a20) {
            if (ds_U < -1e-12f) rmin = fminf(rmin, -s_U * frcp(ds_U));
            if (dl_U < -1e-12f) rmin = fminf(rmin, -l_U * frcp(dl_U));
        }
        const float alpha = 0.99f * wave_min(rmin);

        s_B += alpha * ds_B; s_C += alpha * ds_C; s_D += alpha * ds_D;
        s_E += alpha * ds_E; s_U += alpha * ds_U;
        l_B += alpha * dl_B; l_C += alpha * dl_C; l_D += alpha * dl_D;
        l_E += alpha * dl_E; l_U += alpha * dl_U;
        w2a += alpha * dw2a; w2b += alpha * dw2b;
        #pragma unroll
        for (int r = 0; r < 10; ++r) w1[r] += alpha * dw1[r];
        w1own += alpha * dOwn;
        nu += alpha * nu_d;
    }

    // ---------------- epilogue: cost ----------------
    if (lane == 0) {
        #pragma unroll
        for (int r = 0; r < 10; ++r) wL[r] = w1[r];
    }
    __syncthreads();
    float part = a40 ? (w2a * w2a + w2b * w2b) : 0.f;
    for (int idx = lane; idx < 100; idx += 64) {
        const int r = idx / 10, c = idx - r * 10;
        part += wL[r] * QhL[r * 12 + c] * wL[c];
    }
    if (lane < 10) part += pvL[lane] * wL[lane];
    for (int idx = lane; idx < 160; idx += 64) {
        const int i2 = idx >> 4, rc = idx & 15, rr2 = rc >> 2, cc2 = rc & 3;
        part += axL[i2 * 4 + rr2] * QL[rc] * axL[i2 * 4 + cc2];
    }
    if (lane == 0) {
        float ct = 0.f;
        #pragma unroll
        for (int r = 0; r < 4; ++r) {
            const float xr = (r == 0 ? xv0 : r == 1 ? xv1 : r == 2 ? xv2 : xv3);
            #pragma unroll
            for (int c = 0; c < 4; ++c) {
                const float xc = (c == 0 ? xv0 : c == 1 ? xv1 : c == 2 ? xv2 : xv3);
                ct += xr * QL[r * 4 + c] * xc;
            }
        }
        part += ct;
    }
    const float cost = wave_sum(part);
    if (lane == 0) {
        out[item] = cost;
        out[BATCH + item] = w1[0];
    }
}

extern "C" void kernel_launch(void* const* d_in, const int* in_sizes, int n_in,
                              void* d_out, int out_size, void* d_ws, size_t ws_size,
                              hipStream_t stream) {
    const float* x  = (const float*)d_in[0];
    const float* u0 = (const float*)d_in[1];
    const float* Qs = (const float*)d_in[2];
    const float* Rs = (const float*)d_in[3];
    const float* Ad = (const float*)d_in[4];
    const float* Bd = (const float*)d_in[5];
    float* outp = (float*)d_out;
    ipm_kernel<<<dim3(BATCH), dim3(64), 0, stream>>>(x, u0, Qs, Rs, Ad, Bd, outp);
}

// Round 5
// 101.267 us; speedup vs baseline: 2.3961x; 1.0014x over previous
//
#include <hip/hip_runtime.h>

#define BATCH 1024
#define ITERS 20
#define SIGMA_C 0.1f
#define REG_C 1e-8f

__device__ __forceinline__ float frcp(float x) { return __builtin_amdgcn_rcpf(x); }
__device__ __forceinline__ float readlane_f(float v, int l) {
    return __int_as_float(__builtin_amdgcn_readlane(__float_as_int(v), l));
}
// DPP helper: ctrl must be a literal
#define DPPF(v, ctrl) \
    __int_as_float(__builtin_amdgcn_update_dpp(0, __float_as_int(v), ctrl, 0xf, 0xf, true))

__device__ __forceinline__ float wave_sum(float v) {
    v += DPPF(v, 0xB1);   // quad_perm 1,0,3,2
    v += DPPF(v, 0x4E);   // quad_perm 2,3,0,1
    v += DPPF(v, 0x141);  // row_half_mirror
    v += DPPF(v, 0x140);  // row_mirror
    v += __shfl_xor(v, 16);
    v += __shfl_xor(v, 32);
    return v;
}

// fused 4-stream reduction step (3 sums + 1 min)
#define RED4_DPP(ctrl) do { \
    p0 += DPPF(p0, ctrl); \
    p1 += DPPF(p1, ctrl); \
    p2 += DPPF(p2, ctrl); \
    rmin = fminf(rmin, DPPF(rmin, ctrl)); \
} while (0)

// One wave (64 lanes) per batch item. Lane k<40 owns constraint rows
// {B:20+k, C:60+k, D:100+k, E:140+k} and e-vars w2a=w[10+k], w2b=w[50+k].
// Lanes<20 own the u-box rows. w1[10] replicated in all lanes.
// S-formation: lanes 0-49 each own 2 adjacent S entries (register-cached
// outer-product rows), lanes 50-59 own the 10 rhs entries.
// Solve: 2x2-block Gauss-Jordan, rows on lanes 0-9, solution replicated.
__global__ __launch_bounds__(64, 1) void ipm_kernel(
    const float* __restrict__ x, const float* __restrict__ u0p,
    const float* __restrict__ Qs, const float* __restrict__ Rs,
    const float* __restrict__ Ad, const float* __restrict__ Bd,
    float* __restrict__ out)
{
    const int item = blockIdx.x;
    const int lane = threadIdx.x;

    __shared__ __align__(16) float BLc[10 * 40];  // B column-major: BLc[j][k]=B[k][j]
    __shared__ __align__(16) float QBc[10 * 40];  // (Q_diag B) column-major
    __shared__ __align__(16) float yL4[40];
    __shared__ __align__(16) float QhL[10 * 12];
    __shared__ __align__(16) float SL[10 * 12];   // col 10 = rhs
    __shared__ __align__(16) float cg[80];        // [0,40)=coeff, [40,80)=gvc
    __shared__ float duL[20], ltL[20];
    __shared__ float axL[40];
    __shared__ float pvL[10], wL[10];
    __shared__ float QL[16];
    __shared__ float TL[40];    // T[i][r] = (A^i B)[r]
    __shared__ float AhL[160];  // A_hat [40][4]

    // ---------------- prologue ----------------
    const int r2 = (lane >> 2) & 3, c2 = lane & 3;
    const int r4 = lane & 3;

    if (lane < 16) {
        float acc = 0.f;
        #pragma unroll
        for (int k = 0; k < 4; ++k) acc += Qs[r2 * 4 + k] * Qs[c2 * 4 + k];
        QL[lane] = acc;
    }

    // A powers -> A_hat (shfl chain)
    float acol[4];
    #pragma unroll
    for (int k = 0; k < 4; ++k) acol[k] = Ad[k * 4 + c2];
    float cur = Ad[r2 * 4 + c2];
    if (lane < 16) AhL[r2 * 4 + c2] = cur;
    #pragma unroll
    for (int i = 1; i < 10; ++i) {
        float nx = 0.f;
        #pragma unroll
        for (int k = 0; k < 4; ++k) nx += __shfl(cur, r2 * 4 + k) * acol[k];
        cur = nx;
        if (lane < 16) AhL[(4 * i + r2) * 4 + c2] = cur;
    }

    // T chain
    float arow[4];
    #pragma unroll
    for (int k = 0; k < 4; ++k) arow[k] = Ad[r4 * 4 + k];
    float tc = Bd[r4];
    if (lane < 4) TL[r4] = tc;
    #pragma unroll
    for (int i = 1; i < 10; ++i) {
        float nt = 0.f;
        #pragma unroll
        for (int k = 0; k < 4; ++k) nt += arow[k] * __shfl(tc, k);
        tc = nt;
        if (lane < 4) TL[i * 4 + r4] = nt;
    }
    __syncthreads();

    // per-lane B_hat row
    const int kk40 = (lane < 40) ? lane : 39;
    const int ib = lane >> 2;
    float b[10];
    #pragma unroll
    for (int j = 0; j < 10; ++j) {
        int dd = ib - j;
        int dc = dd < 0 ? 0 : (dd > 9 ? 9 : dd);
        float v = TL[dc * 4 + r4];
        b[j] = (dd >= 0 && lane < 40) ? v : 0.f;
    }

    const float xv0 = x[item * 4 + 0], xv1 = x[item * 4 + 1];
    const float xv2 = x[item * 4 + 2], xv3 = x[item * 4 + 3];
    const float ax = AhL[kk40 * 4 + 0] * xv0 + AhL[kk40 * 4 + 1] * xv1 +
                     AhL[kk40 * 4 + 2] * xv2 + AhL[kk40 * 4 + 3] * xv3;
    if (lane < 40) axL[lane] = ax;

    const int gbase = lane & ~3;
    float yv = 0.f;
    #pragma unroll
    for (int rp_ = 0; rp_ < 4; ++rp_) yv += QL[r4 * 4 + rp_] * __shfl(ax, gbase + rp_);
    if (lane < 40) yL4[lane] = yv;
    #pragma unroll
    for (int cc = 0; cc < 10; ++cc) {
        float acc = 0.f;
        #pragma unroll
        for (int rp_ = 0; rp_ < 4; ++rp_) acc += QL[r4 * 4 + rp_] * __shfl(b[cc], gbase + rp_);
        if (lane < 40) QBc[cc * 40 + lane] = acc;
    }
    if (lane < 40) {
        #pragma unroll
        for (int j = 0; j < 10; ++j) BLc[j * 40 + lane] = b[j];
    }
    __syncthreads();

    // pv (lanes 0-9)
    if (lane < 10) {
        const float4* br = reinterpret_cast<const float4*>(&BLc[lane * 40]);
        const float4* yy = reinterpret_cast<const float4*>(yL4);
        float acc = 0.f;
        #pragma unroll
        for (int i = 0; i < 10; ++i) {
            const float4 a_ = br[i], b_ = yy[i];
            acc += a_.x * b_.x + a_.y * b_.y + a_.z * b_.z + a_.w * b_.w;
        }
        pvL[lane] = 2.f * acc;
    }
    // Qh (100 tasks)
    const float R2v = Rs[0] * Rs[0];
    #pragma unroll
    for (int p = 0; p < 2; ++p) {
        const int t = lane + 64 * p;
        if (t < 100) {
            const int aa = t / 10, bb = t - aa * 10;
            const float4* ba = reinterpret_cast<const float4*>(&BLc[aa * 40]);
            const float4* qb = reinterpret_cast<const float4*>(&QBc[bb * 40]);
            float acc = (aa == bb) ? R2v : 0.f;
            #pragma unroll
            for (int i = 0; i < 10; ++i) {
                const float4 a_ = ba[i], b_ = qb[i];
                acc += a_.x * b_.x + a_.y * b_.y + a_.z * b_.z + a_.w * b_.w;
            }
            QhL[aa * 12 + bb] = acc;
        }
    }
    __syncthreads();

    // ---------------- per-lane register task caches ----------------
    const int t1 = 2 * lane;
    const int srow = t1 / 10, sc1 = t1 - srow * 10, sc2 = sc1 + 1;
    const int rr = lane - 50;
    float tabA[40], tabB[40];
    float qh_a = 0.f, qh_b = 0.f;
    bool diagA = false, diagB = false;
    int drow = 0;
    if (lane < 50) {
        const float4* br = reinterpret_cast<const float4*>(&BLc[srow * 40]);
        const float4* b1 = reinterpret_cast<const float4*>(&BLc[sc1 * 40]);
        const float4* b2 = reinterpret_cast<const float4*>(&BLc[sc2 * 40]);
        #pragma unroll
        for (int i = 0; i < 10; ++i) {
            const float4 r_ = br[i], u_ = b1[i], v_ = b2[i];
            tabA[4*i+0] = r_.x * u_.x; tabA[4*i+1] = r_.y * u_.y;
            tabA[4*i+2] = r_.z * u_.z; tabA[4*i+3] = r_.w * u_.w;
            tabB[4*i+0] = r_.x * v_.x; tabB[4*i+1] = r_.y * v_.y;
            tabB[4*i+2] = r_.z * v_.z; tabB[4*i+3] = r_.w * v_.w;
        }
        qh_a = 2.f * QhL[srow * 12 + sc1];
        qh_b = 2.f * QhL[srow * 12 + sc2];
        diagA = (srow == sc1); diagB = (srow == sc2);
        drow = srow;
    } else if (lane < 60) {
        const float4* br = reinterpret_cast<const float4*>(&BLc[rr * 40]);
        #pragma unroll
        for (int i = 0; i < 10; ++i) {
            const float4 r_ = br[i];
            tabA[4*i+0] = r_.x; tabA[4*i+1] = r_.y;
            tabA[4*i+2] = r_.z; tabA[4*i+3] = r_.w;
        }
        #pragma unroll
        for (int c = 0; c < 10; ++c) tabB[c] = QhL[rr * 12 + c];
        qh_a = pvL[rr];
    }
    __syncthreads();

    // ---------------- state init ----------------
    float s_B = fmaxf(4.f - ax, 1.f), s_C = fmaxf(4.f + ax, 1.f);
    float s_D = 1.f, s_E = 1.f, s_U = 1.f;
    float l_B = 1.f, l_C = 1.f, l_D = 1.f, l_E = 1.f, l_U = 1.f;
    float w2a = 0.f, w2b = 0.f;
    float w1[10];
    #pragma unroll
    for (int r = 0; r < 10; ++r) w1[r] = 0.f;
    float w1own = 0.f, nu = 0.f;
    const float uu0 = u0p[item];
    const bool a40 = lane < 40, a20 = lane < 20;
    const int jown = (lane < 10) ? lane : lane - 10;
    const float sgnU = (lane < 10) ? 1.f : -1.f;

    // initial mu = SIGMA * sum(s*l)/180
    float mu;
    {
        float part = a40 ? (s_B * l_B + s_C * l_C + s_D * l_D + s_E * l_E) : 0.f;
        if (a20) part += s_U * l_U;
        mu = SIGMA_C * wave_sum(part) * (1.f / 180.f);
    }

    // ---------------- IPM iterations ----------------
    for (int it = 0; it < ITERS; ++it) {
        const float rs_B = frcp(s_B), rs_C = frcp(s_C), rs_D = frcp(s_D),
                    rs_E = frcp(s_E), rs_U = frcp(s_U);
        const float d_B = l_B * rs_B, d_C = l_C * rs_C, d_D = l_D * rs_D,
                    d_E = l_E * rs_E, d_U = l_U * rs_U;

        float Bu = 0.f;
        #pragma unroll
        for (int j = 0; j < 10; ++j) Bu += b[j] * w1[j];

        const float rp_B = Bu - w2a + s_B - (4.f - ax);
        const float rp_C = -Bu - w2b + s_C - (4.f + ax);
        const float rp_D = -w2a + s_D;
        const float rp_E = -w2b + s_E;
        const float rp_U = sgnU * w1own + s_U - 0.5f;

        const float tm_B = (mu - l_B * s_B + l_B * rp_B) * rs_B;
        const float tm_C = (mu - l_C * s_C + l_C * rp_C) * rs_C;
        const float tm_D = (mu - l_D * s_D + l_D * rp_D) * rs_D;
        const float tm_E = (mu - l_E * s_E + l_E * rp_E) * rs_E;
        const float tm_U = (mu - l_U * s_U + l_U * rp_U) * rs_U;
        const float lt_B = l_B + tm_B, lt_C = l_C + tm_C, lt_D = l_D + tm_D,
                    lt_E = l_E + tm_E;

        const float D22a = 2.f + d_B + d_D + REG_C, D22b = 2.f + d_C + d_E + REG_C;
        const float rda = frcp(D22a), rdb = frcp(D22b);
        const float rw2a = -2.f * w2a + lt_B + lt_D;
        const float rw2b = -2.f * w2b + lt_C + lt_E;
        const float coeff = (d_B + d_C) - d_B * d_B * rda - d_C * d_C * rdb;
        const float gvc = (d_B * rw2a * rda - d_C * rw2b * rdb) - (lt_B - lt_C);

        if (a40) { cg[lane] = coeff; cg[40 + lane] = gvc; }
        if (a20) { duL[lane] = d_U; ltL[lane] = l_U + tm_U; }
        __syncthreads();

        // ---- S + rhs formation (register tables, broadcast coeff reads) ----
        float4 cf[10];
        {
            const float4* cp = reinterpret_cast<const float4*>(cg + ((lane >= 50) ? 40 : 0));
            #pragma unroll
            for (int i = 0; i < 10; ++i) cf[i] = cp[i];
        }
        if (lane < 50) {
            float accA = 0.f, accB = 0.f;
            #pragma unroll
            for (int i = 0; i < 10; ++i) {
                accA += tabA[4*i+0]*cf[i].x + tabA[4*i+1]*cf[i].y +
                        tabA[4*i+2]*cf[i].z + tabA[4*i+3]*cf[i].w;
                accB += tabB[4*i+0]*cf[i].x + tabB[4*i+1]*cf[i].y +
                        tabB[4*i+2]*cf[i].z + tabB[4*i+3]*cf[i].w;
            }
            float vA = accA + qh_a, vB = accB + qh_b;
            if (diagA || diagB) {
                const float dd = duL[drow] + duL[10 + drow] + REG_C;
                if (diagA) vA += dd; else vB += dd;
            }
            *reinterpret_cast<float2*>(&SL[srow * 12 + sc1]) = make_float2(vA, vB);
        } else if (lane < 60) {
            float acc = 0.f;
            #pragma unroll
            for (int i = 0; i < 10; ++i)
                acc += tabA[4*i+0]*cf[i].x + tabA[4*i+1]*cf[i].y +
                       tabA[4*i+2]*cf[i].z + tabA[4*i+3]*cf[i].w;
            float qw = 0.f;
            #pragma unroll
            for (int c = 0; c < 10; ++c) qw += tabB[c] * w1[c];
            SL[rr * 12 + 10] =
                acc - (2.f * qw + qh_a + ltL[rr] - ltL[10 + rr] + ((rr == 0) ? nu : 0.f));
        }
        __syncthreads();

        // ---- 2x2-block Gauss-Jordan: rows on lanes 0-9, cols [S|rhsA|rhsB] ----
        float row[12];
        if (lane < 10) {
            const float4* s4 = reinterpret_cast<const float4*>(&SL[lane * 12]);
            const float4 q0 = s4[0], q1 = s4[1], q2 = s4[2];
            row[0] = q0.x; row[1] = q0.y; row[2] = q0.z; row[3] = q0.w;
            row[4] = q1.x; row[5] = q1.y; row[6] = q1.z; row[7] = q1.w;
            row[8] = q2.x; row[9] = q2.y; row[10] = q2.z;
        } else {
            #pragma unroll
            for (int c = 0; c < 11; ++c) row[c] = 0.f;
        }
        row[11] = (lane == 0) ? 1.f : 0.f;

        #pragma unroll
        for (int kb = 0; kb < 5; ++kb) {
            const int bb = 2 * kb;
            float pA[12], pB[12];
            #pragma unroll
            for (int c = 0; c < 12; ++c) {
                if (c >= bb) {
                    pA[c] = readlane_f(row[c], bb);
                    pB[c] = readlane_f(row[c], bb + 1);
                }
            }
            const float rdet = frcp(pA[bb] * pB[bb + 1] - pA[bb + 1] * pB[bb]);
            const bool act = (lane < 10) && (lane != bb) && (lane != bb + 1);
            const float f1 = act ? (row[bb] * pB[bb + 1] - row[bb + 1] * pB[bb]) * rdet : 0.f;
            const float f2 = act ? (row[bb + 1] * pA[bb] - row[bb] * pA[bb + 1]) * rdet : 0.f;
            #pragma unroll
            for (int c = 0; c < 12; ++c) {
                if (c >= bb + 2) row[c] -= f1 * pA[c] + f2 * pB[c];
            }
        }

        // final independent 2x2 block solves -> solution replicated in all lanes
        float xA[10], xB[10];
        #pragma unroll
        for (int kb = 0; kb < 5; ++kb) {
            const int bb = 2 * kb;
            const float a_  = readlane_f(row[bb],     bb);
            const float b_  = readlane_f(row[bb + 1], bb);
            const float c_  = readlane_f(row[bb],     bb + 1);
            const float d_  = readlane_f(row[bb + 1], bb + 1);
            const float rA0 = readlane_f(row[10], bb),     rB0 = readlane_f(row[11], bb);
            const float rA1 = readlane_f(row[10], bb + 1), rB1 = readlane_f(row[11], bb + 1);
            const float rdet = frcp(a_ * d_ - b_ * c_);
            xA[bb]     = (d_ * rA0 - b_ * rA1) * rdet;
            xA[bb + 1] = (a_ * rA1 - c_ * rA0) * rdet;
            xB[bb]     = (d_ * rB0 - b_ * rB1) * rdet;
            xB[bb + 1] = (a_ * rB1 - c_ * rB0) * rdet;
        }

        const float rn = -(w1[0] - uu0);
        const float nu_d = (xA[0] - rn) * frcp(xB[0] + REG_C);
        float dw1[10];
        #pragma unroll
        for (int r = 0; r < 10; ++r) dw1[r] = xA[r] - nu_d * xB[r];
        float dOwn = 0.f;
        #pragma unroll
        for (int r = 0; r < 10; ++r) dOwn = (jown == r) ? dw1[r] : dOwn;

        float Bdw = 0.f;
        #pragma unroll
        for (int j = 0; j < 10; ++j) Bdw += b[j] * dw1[j];
        const float dw2a = (rw2a + d_B * Bdw) * rda;
        const float dw2b = (rw2b - d_C * Bdw) * rdb;

        const float ds_B = -(Bdw - dw2a) - rp_B;
        const float ds_C = (Bdw + dw2b) - rp_C;
        const float ds_D = dw2a - rp_D;
        const float ds_E = dw2b - rp_E;
        const float ds_U = -sgnU * dOwn - rp_U;
        const float dl_B = (mu - l_B * s_B - l_B * ds_B) * rs_B;
        const float dl_C = (mu - l_C * s_C - l_C * ds_C) * rs_C;
        const float dl_D = (mu - l_D * s_D - l_D * ds_D) * rs_D;
        const float dl_E = (mu - l_E * s_E - l_E * ds_E) * rs_E;
        const float dl_U = (mu - l_U * s_U - l_U * ds_U) * rs_U;

        // ---- fused 4-stream reduction: rmin (alpha) + P0,P1,P2 (next mu) ----
        float rmin = 1.f, p0 = 0.f, p1 = 0.f, p2 = 0.f;
        if (a40) {
            if (ds_B < -1e-12f) rmin = fminf(rmin, -s_B * frcp(ds_B));
            if (ds_C < -1e-12f) rmin = fminf(rmin, -s_C * frcp(ds_C));
            if (ds_D < -1e-12f) rmin = fminf(rmin, -s_D * frcp(ds_D));
            if (ds_E < -1e-12f) rmin = fminf(rmin, -s_E * frcp(ds_E));
            if (dl_B < -1e-12f) rmin = fminf(rmin, -l_B * frcp(dl_B));
            if (dl_C < -1e-12f) rmin = fminf(rmin, -l_C * frcp(dl_C));
            if (dl_D < -1e-12f) rmin = fminf(rmin, -l_D * frcp(dl_D));
            if (dl_E < -1e-12f) rmin = fminf(rmin, -l_E * frcp(dl_E));
            p0 = s_B * l_B + s_C * l_C + s_D * l_D + s_E * l_E;
            p1 = (s_B * dl_B + l_B * ds_B) + (s_C * dl_C + l_C * ds_C) +
                 (s_D * dl_D + l_D * ds_D) + (s_E * dl_E + l_E * ds_E);
            p2 = ds_B * dl_B + ds_C * dl_C + ds_D * dl_D + ds_E * dl_E;
        }
        if (a20) {
            if (ds_U < -1e-12f) rmin = fminf(rmin, -s_U * frcp(ds_U));
            if (dl_U < -1e-12f) rmin = fminf(rmin, -l_U * frcp(dl_U));
            p0 += s_U * l_U;
            p1 += s_U * dl_U + l_U * ds_U;
            p2 += ds_U * dl_U;
        }
        RED4_DPP(0xB1);
        RED4_DPP(0x4E);
        RED4_DPP(0x141);
        RED4_DPP(0x140);
        p0 += __shfl_xor(p0, 16); p1 += __shfl_xor(p1, 16); p2 += __shfl_xor(p2, 16);
        rmin = fminf(rmin, __shfl_xor(rmin, 16));
        p0 += __shfl_xor(p0, 32); p1 += __shfl_xor(p1, 32); p2 += __shfl_xor(p2, 32);
        rmin = fminf(rmin, __shfl_xor(rmin, 32));

        const float alpha = 0.99f * rmin;
        mu = SIGMA_C * (p0 + alpha * (p1 + alpha * p2)) * (1.f / 180.f);

        s_B += alpha * ds_B; s_C += alpha * ds_C; s_D += alpha * ds_D;
        s_E += alpha * ds_E; s_U += alpha * ds_U;
        l_B += alpha * dl_B; l_C += alpha * dl_C; l_D += alpha * dl_D;
        l_E += alpha * dl_E; l_U += alpha * dl_U;
        w2a += alpha * dw2a; w2b += alpha * dw2b;
        #pragma unroll
        for (int r = 0; r < 10; ++r) w1[r] += alpha * dw1[r];
        w1own += alpha * dOwn;
        nu += alpha * nu_d;
    }

    // ---------------- epilogue: cost ----------------
    if (lane == 0) {
        #pragma unroll
        for (int r = 0; r < 10; ++r) wL[r] = w1[r];
    }
    __syncthreads();
    float part = a40 ? (w2a * w2a + w2b * w2b) : 0.f;
    for (int idx = lane; idx < 100; idx += 64) {
        const int r = idx / 10, c = idx - r * 10;
        part += wL[r] * QhL[r * 12 + c] * wL[c];
    }
    if (lane < 10) part += pvL[lane] * wL[lane];
    for (int idx = lane; idx < 160; idx += 64) {
        const int i2 = idx >> 4, rc = idx & 15, rr2 = rc >> 2, cc2 = rc & 3;
        part += axL[i2 * 4 + rr2] * QL[rc] * axL[i2 * 4 + cc2];
    }
    if (lane == 0) {
        float ct = 0.f;
        #pragma unroll
        for (int r = 0; r < 4; ++r) {
            const float xr = (r == 0 ? xv0 : r == 1 ? xv1 : r == 2 ? xv2 : xv3);
            #pragma unroll
            for (int c = 0; c < 4; ++c) {
                const float xc = (c == 0 ? xv0 : c == 1 ? xv1 : c == 2 ? xv2 : xv3);
                ct += xr * QL[r * 4 + c] * xc;
            }
        }
        part += ct;
    }
    const float cost = wave_sum(part);
    if (lane == 0) {
        out[item] = cost;
        out[BATCH + item] = w1[0];
    }
}

extern "C" void kernel_launch(void* const* d_in, const int* in_sizes, int n_in,
                              void* d_out, int out_size, void* d_ws, size_t ws_size,
                              hipStream_t stream) {
    const float* x  = (const float*)d_in[0];
    const float* u0 = (const float*)d_in[1];
    const float* Qs = (const float*)d_in[2];
    const float* Rs = (const float*)d_in[3];
    const float* Ad = (const float*)d_in[4];
    const float* Bd = (const float*)d_in[5];
    float* outp = (float*)d_out;
    ipm_kernel<<<dim3(BATCH), dim3(64), 0, stream>>>(x, u0, Qs, Rs, Ad, Bd, outp);
}